// Round 13
// baseline (109.196 us; speedup 1.0000x reference)
//
#include <hip/hip_runtime.h>

#define EPS 1e-12f

// MovingAvgNormNonBias: x [B=32, T=3000, D=512] fp32, k=100.
// Two-pass (R6 structure — empirically the fastest host structure):
//   k1: 25-row segment sums (s1,s2) per (b,seg,d4-col) into d_ws.
//   k2: 128-thr/2-wave blocks, one 25-row chunk each (3840 blocks, ~7680
//       waves). Interior: init from 4 ws segment sums; 3x-unrolled streaming
//       loop, reload-after-use register pipeline (9 f4 in flight, ~52 VGPR,
//       keeps 8 waves/SIMD). rsqrt fast path, nontemporal stores.
// XCD swizzle keeps adjacent chunks of one batch on one XCD (stream overlap).

typedef float f4 __attribute__((ext_vector_type(4)));

constexpr int Bq = 32, Tq = 3000, Dq = 512;
constexpr int SEGR = 25;             // rows per chunk
constexpr int NSEG = Tq / SEGR;      // 120
constexpr int NCHUNK = Tq / SEGR;    // 120
constexpr int NBm = Bq * NCHUNK;     // 3840 mavn blocks
constexpr int NXCD = 8;

__global__ __launch_bounds__(128) void seg_sums_kernel(
    const float* __restrict__ x, float* __restrict__ ws)
{
    const int s = blockIdx.x;          // segment 0..NSEG-1
    const int b = blockIdx.y;
    const int d4 = threadIdx.x;        // 0..127
    const float* xp = x + ((size_t)b * Tq) * Dq + (size_t)d4 * 4;

    f4 a1 = {0.f, 0.f, 0.f, 0.f};
    f4 a2 = a1, b1 = a1, b2 = a1;
    const int r0 = s * SEGR;
#pragma unroll 5
    for (int j = 0; j < SEGR; j += 2) {
        const f4 v = *(const f4*)(xp + (size_t)(r0 + j) * Dq);
        a1 += v; a2 += v * v;
        if (j + 1 < SEGR) {
            const f4 w = *(const f4*)(xp + (size_t)(r0 + j + 1) * Dq);
            b1 += w; b2 += w * w;
        }
    }
    f4* w1 = (f4*)ws;                          // [B][NSEG][128]
    f4* w2 = w1 + (size_t)Bq * NSEG * (Dq / 4);
    const size_t idx = ((size_t)b * NSEG + s) * (Dq / 4) + d4;
    w1[idx] = a1 + b1;
    w2[idx] = a2 + b2;
}

__global__ __launch_bounds__(128) void mavn_kernel(
    const float* __restrict__ x, const int* __restrict__ kptr,
    float* __restrict__ out, const float* __restrict__ ws, int use_seg)
{
    // XCD-swizzled decode of (b, chunk)
    const int g = blockIdx.x;                  // 0..NBm-1
    const int xcd = g & (NXCD - 1);
    const int slot = g >> 3;
    const int pair = xcd * (NBm / NXCD) + slot;
    const int b = pair / NCHUNK;
    const int c = pair % NCHUNK;
    const int t0 = c * SEGR;
    const int t1 = t0 + SEGR;

    const int k = kptr[0];
    const int half = k >> 1;
    const int d4 = threadIdx.x;
    const size_t base = ((size_t)b * Tq) * (size_t)Dq + (size_t)d4 * 4;
    const float* xp = x + base;
    float* op = out + base;

    const float kf = (float)k;
    const float inv_km1 = 1.0f / (float)(k - 1);
    const int tail_start = Tq - (k - half);

    const bool seg_ok = use_seg && (k == 4 * SEGR);
    // interior: full window in-bounds AND denom == k for every t in chunk
    const bool interior = seg_ok && (t0 >= half) &&
                          (t0 + SEGR - 1 + (k - half) - 1 <= Tq - 1) &&
                          (t0 + SEGR - 1 < tail_start);

    if (interior) {
        // init from ws segment sums: window [t0-50, t0+49] = segs c-2..c+1
        const f4* w1 = (const f4*)ws;
        const f4* w2 = w1 + (size_t)Bq * NSEG * (Dq / 4);
        f4 s1 = {0.f, 0.f, 0.f, 0.f};
        f4 s2 = s1;
#pragma unroll
        for (int i = 0; i < 4; ++i) {
            const size_t idx = ((size_t)b * NSEG + (c - 2 + i)) * (Dq / 4) + d4;
            s1 += w1[idx];
            s2 += w2[idx];
        }
        const float inv_k = 1.0f / kf;
        // peel j = 0
        {
            const f4 xc = *(const f4*)(xp + (size_t)t0 * Dq);
            f4 o;
#pragma unroll
            for (int cc = 0; cc < 4; ++cc) {
                const float m = s1[cc] * inv_k;
                float var_sum = s2[cc] - m * s1[cc];
                var_sum = fmaxf(var_sum, 1e-12f);
                const float r = __builtin_amdgcn_rsqf(var_sum * inv_km1);
                o[cc] = (xc[cc] - m) * r;
            }
            __builtin_nontemporal_store(o, (f4*)(op + (size_t)t0 * Dq));
        }
        // 3x-unrolled pipelined j = 1..24 (8 groups of 3, exact).
        // Reload-after-use: 9 f4 regs (n0..2,i0..2,o0..2) hold group gg's rows;
        // each is reloaded for group gg+1 right after its use -> distance 3 steps.
        const int inoff = (k - half) - 1;      // +49
        const int oboff = -(half + 1);         // -51
        f4 n0 = *(const f4*)(xp + (size_t)(t0 + 1) * Dq);
        f4 n1 = *(const f4*)(xp + (size_t)(t0 + 2) * Dq);
        f4 n2 = *(const f4*)(xp + (size_t)(t0 + 3) * Dq);
        f4 i0 = *(const f4*)(xp + (size_t)(t0 + 1 + inoff) * Dq);
        f4 i1 = *(const f4*)(xp + (size_t)(t0 + 2 + inoff) * Dq);
        f4 i2 = *(const f4*)(xp + (size_t)(t0 + 3 + inoff) * Dq);
        f4 o0 = *(const f4*)(xp + (size_t)(t0 + 1 + oboff) * Dq);
        f4 o1 = *(const f4*)(xp + (size_t)(t0 + 2 + oboff) * Dq);
        f4 o2 = *(const f4*)(xp + (size_t)(t0 + 3 + oboff) * Dq);
#pragma unroll
        for (int gg = 0; gg < 8; ++gg) {
            const int j0 = 1 + 3 * gg;
            const int jn = (gg < 7) ? j0 + 3 : j0;   // last group: reload self (L1-hot)
            // ---- step r = 0 (row j0) ----
            {
                s1 += i0 - o0;
                s2 += i0 * i0 - o0 * o0;
                f4 o;
#pragma unroll
                for (int cc = 0; cc < 4; ++cc) {
                    const float m = s1[cc] * inv_k;
                    float var_sum = s2[cc] - m * s1[cc];
                    var_sum = fmaxf(var_sum, 1e-12f);
                    const float r = __builtin_amdgcn_rsqf(var_sum * inv_km1);
                    o[cc] = (n0[cc] - m) * r;
                }
                __builtin_nontemporal_store(o, (f4*)(op + (size_t)(t0 + j0) * Dq));
                n0 = *(const f4*)(xp + (size_t)(t0 + jn) * Dq);
                i0 = *(const f4*)(xp + (size_t)(t0 + jn + inoff) * Dq);
                o0 = *(const f4*)(xp + (size_t)(t0 + jn + oboff) * Dq);
            }
            // ---- step r = 1 (row j0+1) ----
            {
                s1 += i1 - o1;
                s2 += i1 * i1 - o1 * o1;
                f4 o;
#pragma unroll
                for (int cc = 0; cc < 4; ++cc) {
                    const float m = s1[cc] * inv_k;
                    float var_sum = s2[cc] - m * s1[cc];
                    var_sum = fmaxf(var_sum, 1e-12f);
                    const float r = __builtin_amdgcn_rsqf(var_sum * inv_km1);
                    o[cc] = (n1[cc] - m) * r;
                }
                __builtin_nontemporal_store(o, (f4*)(op + (size_t)(t0 + j0 + 1) * Dq));
                n1 = *(const f4*)(xp + (size_t)(t0 + jn + 1) * Dq);
                i1 = *(const f4*)(xp + (size_t)(t0 + jn + 1 + inoff) * Dq);
                o1 = *(const f4*)(xp + (size_t)(t0 + jn + 1 + oboff) * Dq);
            }
            // ---- step r = 2 (row j0+2) ----
            {
                s1 += i2 - o2;
                s2 += i2 * i2 - o2 * o2;
                f4 o;
#pragma unroll
                for (int cc = 0; cc < 4; ++cc) {
                    const float m = s1[cc] * inv_k;
                    float var_sum = s2[cc] - m * s1[cc];
                    var_sum = fmaxf(var_sum, 1e-12f);
                    const float r = __builtin_amdgcn_rsqf(var_sum * inv_km1);
                    o[cc] = (n2[cc] - m) * r;
                }
                __builtin_nontemporal_store(o, (f4*)(op + (size_t)(t0 + j0 + 2) * Dq));
                n2 = *(const f4*)(xp + (size_t)(t0 + jn + 2) * Dq);
                i2 = *(const f4*)(xp + (size_t)(t0 + jn + 2 + inoff) * Dq);
                o2 = *(const f4*)(xp + (size_t)(t0 + jn + 2 + oboff) * Dq);
            }
        }
        return;
    }

    // ---- general (edge / k!=100 / no-ws) path: inline init + masked loop ----
    f4 s1 = {0.f, 0.f, 0.f, 0.f};
    f4 s2 = s1;
    {
        const int wlo = (t0 - half > 0) ? t0 - half : 0;
        const int whi = (t0 + (k - half) < Tq) ? t0 + (k - half) : Tq;
        f4 a1 = s1, a2 = s1;
        int j = wlo;
        for (; j + 1 < whi; j += 2) {
            const f4 v = *(const f4*)(xp + (size_t)j * Dq);
            const f4 u = *(const f4*)(xp + (size_t)(j + 1) * Dq);
            s1 += v; s2 += v * v;
            a1 += u; a2 += u * u;
        }
        if (j < whi) {
            const f4 v = *(const f4*)(xp + (size_t)j * Dq);
            s1 += v; s2 += v * v;
        }
        s1 += a1; s2 += a2;
    }

    f4 nx = *(const f4*)(xp + (size_t)t0 * Dq);
    f4 ia = {0.f, 0.f, 0.f, 0.f};
    f4 ob = ia;
    float wa = 0.f, wb = 0.f;

    for (int t = t0; t < t1; ++t) {
        const f4 cnum = nx;
        const f4 cin = ia;
        const f4 cout = ob;
        const float cwa = wa, cwb = wb;

        {
            const int tn = (t + 1 < t1) ? t + 1 : t;
            nx = *(const f4*)(xp + (size_t)tn * Dq);
            int ja = tn + (k - half) - 1;
            int jr = tn - half - 1;
            wa = (ja < Tq && tn > t0) ? 1.f : 0.f;
            wb = (jr >= 0 && tn > t0) ? 1.f : 0.f;
            ja = ja < Tq - 1 ? ja : Tq - 1; ja = ja > 0 ? ja : 0;
            jr = jr > 0 ? jr : 0;
            ia = *(const f4*)(xp + (size_t)ja * Dq);
            ob = *(const f4*)(xp + (size_t)jr * Dq);
        }

        s1 += cwa * cin - cwb * cout;
        s2 += cwa * cin * cin - cwb * cout * cout;

        int idn = half + t;
        idn = idn < k ? idn : k;
        const int tail = (k - 1) - (t - tail_start);
        idn = idn < tail ? idn : tail;
        const float inv_denom = __builtin_amdgcn_rcpf((float)idn);

        f4 o;
#pragma unroll
        for (int cc = 0; cc < 4; ++cc) {
            const float m = s1[cc] * inv_denom;
            float var_sum = s2[cc] - 2.0f * m * s1[cc] + kf * m * m;
            var_sum = fmaxf(var_sum, 0.0f);
            const float sd = __builtin_amdgcn_sqrtf(var_sum * inv_km1);
            o[cc] = (cnum[cc] - m) * __builtin_amdgcn_rcpf(sd + EPS);
        }
        __builtin_nontemporal_store(o, (f4*)(op + (size_t)t * Dq));
    }
}

extern "C" void kernel_launch(void* const* d_in, const int* in_sizes, int n_in,
                              void* d_out, int out_size, void* d_ws, size_t ws_size,
                              hipStream_t stream) {
    const float* x = (const float*)d_in[0];
    const int* kptr = (const int*)d_in[1];
    float* out = (float*)d_out;
    (void)in_sizes; (void)n_in; (void)out_size;

    const size_t ws_need = 2ull * Bq * NSEG * Dq * sizeof(float);  // 15.7 MB
    const int use_seg = (d_ws != nullptr && ws_size >= ws_need) ? 1 : 0;

    if (use_seg) {
        dim3 g1(NSEG, Bq);
        seg_sums_kernel<<<g1, 128, 0, stream>>>(x, (float*)d_ws);
    }
    mavn_kernel<<<NBm, 128, 0, stream>>>(x, kptr, out, (const float*)d_ws, use_seg);
}

// Round 14
// 99.784 us; speedup vs baseline: 1.0943x; 1.0943x over previous
//
#include <hip/hip_runtime.h>

#define EPS 1e-12f

// MovingAvgNormNonBias: x [B=32, T=3000, D=512] fp32, kernel_size k (=100).
// k1: 25-row segment sums (s1, s2) per (b, seg, d4-column) into d_ws.
// k2: one block per (b, 25-row chunk); init = 4 segment sums; software-
//     pipelined streaming loop. Interior chunks (115/120) take an unmasked
//     fast path: denom==k, var = s2 - s1^2/k, rsqrt-based normalize.
// XCD swizzle keeps chunks c-2..c+2 of one batch co-resident on one XCD.
// Session best (R6): 98.8 us. All structural alternatives regressed:
// single-kernel chunked 155, fused cooperative 113, intra-CU sharing 123,
// LDS DMA ring 106, 3x reload-after-use 109.

typedef float f4 __attribute__((ext_vector_type(4)));

constexpr int Bq = 32, Tq = 3000, Dq = 512;
constexpr int SEG = 25;
constexpr int NSEG = Tq / SEG;        // 120
constexpr int NCHUNK = Tq / SEG;      // 120
constexpr int NB = Bq * NCHUNK;       // 3840 blocks for k2
constexpr int NXCD = 8;

__global__ __launch_bounds__(128) void seg_sums_kernel(
    const float* __restrict__ x, float* __restrict__ ws)
{
    const int s = blockIdx.x;          // segment 0..NSEG-1
    const int b = blockIdx.y;
    const int d4 = threadIdx.x;        // 0..127
    const float* xp = x + ((size_t)b * Tq) * Dq + (size_t)d4 * 4;

    f4 a1 = {0.f, 0.f, 0.f, 0.f};
    f4 a2 = a1, b1 = a1, b2 = a1;
    const int r0 = s * SEG;
#pragma unroll 5
    for (int j = 0; j < SEG; j += 2) {
        const f4 v = *(const f4*)(xp + (size_t)(r0 + j) * Dq);
        a1 += v; a2 += v * v;
        if (j + 1 < SEG) {
            const f4 w = *(const f4*)(xp + (size_t)(r0 + j + 1) * Dq);
            b1 += w; b2 += w * w;
        }
    }
    f4* w1 = (f4*)ws;                          // [B][NSEG][128]
    f4* w2 = w1 + (size_t)Bq * NSEG * (Dq / 4);
    const size_t idx = ((size_t)b * NSEG + s) * (Dq / 4) + d4;
    w1[idx] = a1 + b1;
    w2[idx] = a2 + b2;
}

__global__ __launch_bounds__(128) void mavn_kernel(
    const float* __restrict__ x, const int* __restrict__ kptr,
    float* __restrict__ out, const float* __restrict__ ws, int use_seg)
{
    // XCD-swizzled decode of (b, chunk)
    const int g = blockIdx.x;                  // 0..NB-1
    const int xcd = g & (NXCD - 1);
    const int slot = g >> 3;
    const int pair = xcd * (NB / NXCD) + slot;
    const int b = pair / NCHUNK;
    const int c = pair % NCHUNK;
    const int t0 = c * SEG;
    const int t1 = t0 + SEG;

    const int k = kptr[0];
    const int half = k >> 1;
    const int d4 = threadIdx.x;
    const size_t base = ((size_t)b * Tq) * (size_t)Dq + (size_t)d4 * 4;
    const float* xp = x + base;
    float* op = out + base;

    f4 s1 = {0.f, 0.f, 0.f, 0.f};
    f4 s2 = s1;

    const bool seg_ok = use_seg && (k == 4 * SEG);

    if (seg_ok) {
        // window for t0: rows [t0-50, t0+49] == segments c-2..c+1 (clipped)
        const f4* w1 = (const f4*)ws;
        const f4* w2 = w1 + (size_t)Bq * NSEG * (Dq / 4);
        const int slo = (c - 2 < 0) ? 0 : c - 2;
        const int shi = (c + 2 > NSEG) ? NSEG : c + 2;   // exclusive
        for (int s = slo; s < shi; ++s) {
            const size_t idx = ((size_t)b * NSEG + s) * (Dq / 4) + d4;
            s1 += w1[idx];
            s2 += w2[idx];
        }
    } else {
        // generic inline init: rows [t0-half, t0+k-half-1] clipped
        const int wlo = t0 - half;
        const int whi = t0 + (k - half);
        for (int j = (wlo > 0 ? wlo : 0); j < (whi < Tq ? whi : Tq); ++j) {
            const f4 v = *(const f4*)(xp + (size_t)j * Dq);
            s1 += v; s2 += v * v;
        }
    }

    const float kf = (float)k;
    const float inv_km1 = 1.0f / (float)(k - 1);
    const int tail_start = Tq - (k - half);

    // interior: full window in-bounds and denom == k for every t in chunk
    const bool interior = seg_ok && (t0 >= half) &&
                          (t0 + SEG - 1 + (k - half) - 1 <= Tq - 1) &&
                          (t0 + SEG - 1 < tail_start);

    if (interior) {
        const float inv_k = 1.0f / kf;
        // ---- peel j = 0: output from init sums ----
        {
            const f4 xc = *(const f4*)(xp + (size_t)t0 * Dq);
            f4 o;
#pragma unroll
            for (int cc = 0; cc < 4; ++cc) {
                const float m = s1[cc] * inv_k;
                float var_sum = s2[cc] - m * s1[cc];          // == s2 - s1^2/k
                var_sum = fmaxf(var_sum, 1e-12f);
                const float r = __builtin_amdgcn_rsqf(var_sum * inv_km1);
                o[cc] = (xc[cc] - m) * r;
            }
            __builtin_nontemporal_store(o, (f4*)(op + (size_t)t0 * Dq));
        }
        // ---- pipelined j = 1..SEG-1 (12 exact pairs) ----
        const int inoff = (k - half) - 1;      // +49
        const int oboff = -(half + 1);         // -51
        f4 n0 = *(const f4*)(xp + (size_t)(t0 + 1) * Dq);
        f4 n1 = *(const f4*)(xp + (size_t)(t0 + 2) * Dq);
        f4 i0 = *(const f4*)(xp + (size_t)(t0 + 1 + inoff) * Dq);
        f4 i1 = *(const f4*)(xp + (size_t)(t0 + 2 + inoff) * Dq);
        f4 o0 = *(const f4*)(xp + (size_t)(t0 + 1 + oboff) * Dq);
        f4 o1 = *(const f4*)(xp + (size_t)(t0 + 2 + oboff) * Dq);
        for (int j = 1; j < SEG; j += 2) {
            const f4 cn0 = n0, cn1 = n1, ci0 = i0, ci1 = i1, co0 = o0, co1 = o1;
            {
                const int jn = (j + 2 <= SEG - 2) ? j + 2 : j;  // tail: reload (L1-hot)
                n0 = *(const f4*)(xp + (size_t)(t0 + jn) * Dq);
                n1 = *(const f4*)(xp + (size_t)(t0 + jn + 1) * Dq);
                i0 = *(const f4*)(xp + (size_t)(t0 + jn + inoff) * Dq);
                i1 = *(const f4*)(xp + (size_t)(t0 + jn + 1 + inoff) * Dq);
                o0 = *(const f4*)(xp + (size_t)(t0 + jn + oboff) * Dq);
                o1 = *(const f4*)(xp + (size_t)(t0 + jn + 1 + oboff) * Dq);
            }
            // step j
            s1 += ci0 - co0;
            s2 += ci0 * ci0 - co0 * co0;
            f4 oa;
#pragma unroll
            for (int cc = 0; cc < 4; ++cc) {
                const float m = s1[cc] * inv_k;
                float var_sum = s2[cc] - m * s1[cc];
                var_sum = fmaxf(var_sum, 1e-12f);
                const float r = __builtin_amdgcn_rsqf(var_sum * inv_km1);
                oa[cc] = (cn0[cc] - m) * r;
            }
            __builtin_nontemporal_store(oa, (f4*)(op + (size_t)(t0 + j) * Dq));
            // step j+1
            s1 += ci1 - co1;
            s2 += ci1 * ci1 - co1 * co1;
            f4 ob2;
#pragma unroll
            for (int cc = 0; cc < 4; ++cc) {
                const float m = s1[cc] * inv_k;
                float var_sum = s2[cc] - m * s1[cc];
                var_sum = fmaxf(var_sum, 1e-12f);
                const float r = __builtin_amdgcn_rsqf(var_sum * inv_km1);
                ob2[cc] = (cn1[cc] - m) * r;
            }
            __builtin_nontemporal_store(ob2, (f4*)(op + (size_t)(t0 + j + 1) * Dq));
        }
        return;
    }

    // ---- general (edge) path: masked pipelined loop ----
    f4 nx = *(const f4*)(xp + (size_t)t0 * Dq);
    f4 ia = {0.f, 0.f, 0.f, 0.f};
    f4 ob = ia;
    float wa = 0.f, wb = 0.f;

    for (int t = t0; t < t1; ++t) {
        const f4 cnum = nx;
        const f4 cin = ia;
        const f4 cout = ob;
        const float cwa = wa, cwb = wb;

        {
            const int tn = (t + 1 < t1) ? t + 1 : t;
            nx = *(const f4*)(xp + (size_t)tn * Dq);
            int ja = tn + (k - half) - 1;
            int jr = tn - half - 1;
            wa = (ja < Tq && tn > t0) ? 1.f : 0.f;
            wb = (jr >= 0 && tn > t0) ? 1.f : 0.f;
            ja = ja < Tq - 1 ? ja : Tq - 1; ja = ja > 0 ? ja : 0;
            jr = jr > 0 ? jr : 0;
            ia = *(const f4*)(xp + (size_t)ja * Dq);
            ob = *(const f4*)(xp + (size_t)jr * Dq);
        }

        s1 += cwa * cin - cwb * cout;
        s2 += cwa * cin * cin - cwb * cout * cout;

        // branchless denom: ramp half..k-1, flat k, ramp k-1..half
        int idn = half + t;
        idn = idn < k ? idn : k;
        const int tail = (k - 1) - (t - tail_start);
        idn = idn < tail ? idn : tail;
        const float inv_denom = __builtin_amdgcn_rcpf((float)idn);

        f4 o;
#pragma unroll
        for (int cc = 0; cc < 4; ++cc) {
            const float m = s1[cc] * inv_denom;
            float var_sum = s2[cc] - 2.0f * m * s1[cc] + kf * m * m;
            var_sum = fmaxf(var_sum, 0.0f);
            const float sd = __builtin_amdgcn_sqrtf(var_sum * inv_km1);
            o[cc] = (cnum[cc] - m) * __builtin_amdgcn_rcpf(sd + EPS);
        }
        __builtin_nontemporal_store(o, (f4*)(op + (size_t)t * Dq));
    }
}

extern "C" void kernel_launch(void* const* d_in, const int* in_sizes, int n_in,
                              void* d_out, int out_size, void* d_ws, size_t ws_size,
                              hipStream_t stream) {
    const float* x = (const float*)d_in[0];
    const int* kptr = (const int*)d_in[1];
    float* out = (float*)d_out;
    (void)in_sizes; (void)n_in; (void)out_size;

    const size_t ws_need = 2ull * Bq * NSEG * Dq * sizeof(float);  // 15.7 MB
    const int use_seg = (d_ws != nullptr && ws_size >= ws_need) ? 1 : 0;

    if (use_seg) {
        dim3 g1(NSEG, Bq);
        seg_sums_kernel<<<g1, 128, 0, stream>>>(x, (float*)d_ws);
    }
    mavn_kernel<<<NB, 128, 0, stream>>>(x, kptr, out, (const float*)d_ws, use_seg);
}